// Round 8
// baseline (1605.487 us; speedup 1.0000x reference)
//
#include <hip/hip_runtime.h>

// EncoderPlanarLSTM: T=256,B=1024,DX=48,DA=16 (I=64), H=512, Z=32, F=4
// out = [mu(1024x32) | log_var(1024x32) | u(1024x128) | w(1024x128) | b(1024x4)] fp32
//
// R8: 2-group interleave (R7 concept) with spill-safe memory ops.
// 64 groups x 16 batch rows; WG = (pod p 0..31, col-slice gn 0..7 of 64 cols),
// alternates groups gA=p and gB=p+32 sharing resident weights. All loads are
// compiler-tracked (plain / __hip_atomic_load); inline asm only for input-only
// sc0 sc1 stores and the self-contained flag poll.

typedef __attribute__((__ext_vector_type__(8))) short bx8;   // 8 bf16 (4 VGPR)
typedef __attribute__((__ext_vector_type__(4))) float fx4;
typedef unsigned long long u64;

#define NSTEP 256
#define NKT   18          // K-tiles of 32 over K=576 (512 h + 64 y)
#define ROWB  1184        // LDS bytes per A row (1152 data + 32 pad)
#define GREG  18944       // per-group LDS region: 16 rows * 1184
#define TRPO  37888       // transpose slabs at 2*GREG

__device__ __forceinline__ short bf16_of(float f) {
  union { float f; unsigned u; } c; c.f = f;
  unsigned r = c.u + 0x7fffu + ((c.u >> 16) & 1u);   // RNE
  return (short)(r >> 16);
}
__device__ __forceinline__ float fsigmoid(float x) {
  float e = __builtin_amdgcn_exp2f(-1.44269504f * x);
  return __builtin_amdgcn_rcpf(1.0f + e);
}
__device__ __forceinline__ float ftanh_(float x) {
  float e = __builtin_amdgcn_exp2f(2.88539008f * x);
  return 1.0f - 2.0f * __builtin_amdgcn_rcpf(1.0f + e);
}

__device__ __forceinline__ void poll_flags(const unsigned* p, unsigned tgt) {
  unsigned guard = 0;
  for (;;) {
    unsigned v;
    asm volatile("global_load_dword %0, %1, off sc0 sc1\n\ts_waitcnt vmcnt(0)"
                 : "=v"(v) : "v"(p) : "memory");
    if (__all((int)(v >= tgt))) break;
    if (++guard > (1u << 18)) break;      // bail: terminate, never hang
    __builtin_amdgcn_s_sleep(1);
  }
}

// ---------------- pack masked+concat input to bf16, natural time order -------
__global__ __launch_bounds__(256) void pack_y_kernel(
    const float* __restrict__ x, const float* __restrict__ a,
    const float* __restrict__ mk, short* __restrict__ y) {
  const int idx = blockIdx.x * 256 + threadIdx.x;
  const float* xp = x + (size_t)idx * 48;
  const float* mp = mk + (size_t)idx * 48;
  const float* ap = a + (size_t)idx * 16;
  short* yp = y + (size_t)idx * 64;
  float v[64];
#pragma unroll
  for (int j = 0; j < 12; ++j) {
    fx4 xv = *(const fx4*)(xp + j * 4);
    fx4 mv = *(const fx4*)(mp + j * 4);
#pragma unroll
    for (int t = 0; t < 4; ++t) v[j * 4 + t] = xv[t] * mv[t];
  }
#pragma unroll
  for (int j = 0; j < 4; ++j) {
    fx4 av = *(const fx4*)(ap + j * 4);
#pragma unroll
    for (int t = 0; t < 4; ++t) v[48 + j * 4 + t] = av[t];
  }
#pragma unroll
  for (int c = 0; c < 8; ++c) {
    bx8 o;
#pragma unroll
    for (int t = 0; t < 8; ++t) o[t] = bf16_of(v[c * 8 + t]);
    *(bx8*)(yp + c * 8) = o;
  }
}

// ---------------- one half-iteration: compute group X, prefetch group Y ------
__device__ __forceinline__ void do_half(
    int s, bool pub, bool pref,
    int gX, int gY, char* Ash, int regX, int regY, char* trpX,
    const bx8* Bf, const float* bias, float* cstX,
    const short* yslY, const char* hprevY, char* hnextX,
    float* __restrict__ hfinal, unsigned* flagX, const unsigned* pollY, unsigned tgtY,
    int tid, int wv, int l15, int l4, int srow, int sch,
    unsigned xsw, unsigned xm, int colh, int gn)
{
  // 1: Y's y-input (plain load, compiler-tracked; hides under MFMA)
  u64 vy = 0;
  if (pref)
    vy = *(const u64*)((const char*)yslY + (size_t)(gY * 16 + srow) * 128 + sch * 8);

  // 2: MFMA X (A staged in LDS during the previous half)
  fx4 acc[4];
#pragma unroll
  for (int nt = 0; nt < 4; ++nt) {
    fx4 z = {bias[nt], bias[nt], bias[nt], bias[nt]};
    acc[nt] = z;
  }
  const char* abase = Ash + regX + l15 * ROWB;
  const unsigned kbase = (unsigned)(l4 * 16);
#pragma unroll
  for (int kt = 0; kt < NKT; ++kt) {
    bx8 A0 = *(const bx8*)(abase + (int)(((unsigned)(kt * 64) + kbase) ^ xm));
#pragma unroll
    for (int nt = 0; nt < 4; ++nt)
      acc[nt] = __builtin_amdgcn_mfma_f32_16x16x32_bf16(A0, Bf[nt * NKT + kt], acc[nt], 0, 0, 0);
  }

  // 3: gates + state update
  unsigned hs16[4];
#pragma unroll
  for (int r = 0; r < 4; ++r) {
    float gi = acc[0][r], gf = acc[1][r], gg = acc[2][r], go = acc[3][r];
    float c = fsigmoid(gf) * cstX[r] + fsigmoid(gi) * ftanh_(gg);
    cstX[r] = c;
    float h = fsigmoid(go) * ftanh_(c);
    hs16[r] = (unsigned)(unsigned short)bf16_of(h);
    if (!pub) hfinal[(size_t)(gX * 16 + l4 * 4 + r) * 512 + colh] = h;
  }

  // 4: publish X: LDS transpose -> coalesced sc0 sc1 store (input-only asm)
  if (pub) {
#pragma unroll
    for (int r = 0; r < 4; ++r)
      *(unsigned short*)(trpX + (l4 * 4 + r) * 128 + (wv * 16 + l15) * 2) =
          (unsigned short)hs16[r];
    asm volatile("s_waitcnt lgkmcnt(0)" ::: "memory");
    __builtin_amdgcn_sched_barrier(0);
    __builtin_amdgcn_s_barrier();
    u64 pv = *(const u64*)(trpX + srow * 128 + sch * 8);
    char* sb = hnextX + (size_t)(gX * 16 + srow) * 1024 + gn * 128 + sch * 8;
    asm volatile("global_store_dwordx2 %0, %1, off sc0 sc1" :: "v"(sb), "v"(pv) : "memory");
  }

  // 5: poll Y flags; 6: coherent h loads (atomics, compiler-tracked); 7: stage
  if (pref) {
    poll_flags(pollY, tgtY);
    const u64* hq = (const u64*)(hprevY + (size_t)(gY * 16 + srow) * 1024) + sch * 2;
    u64 hv[8];
#pragma unroll
    for (int j = 0; j < 4; ++j) {
      hv[j * 2]     = __hip_atomic_load(hq + j * 32,     __ATOMIC_RELAXED, __HIP_MEMORY_SCOPE_AGENT);
      hv[j * 2 + 1] = __hip_atomic_load(hq + j * 32 + 1, __ATOMIC_RELAXED, __HIP_MEMORY_SCOPE_AGENT);
    }
    char* lb = Ash + regY + srow * ROWB;
#pragma unroll
    for (int j = 0; j < 4; ++j) {
      *(u64*)(lb + (int)(((unsigned)(sch * 16 + j * 256))     ^ xsw)) = hv[j * 2];
      *(u64*)(lb + (int)(((unsigned)(sch * 16 + j * 256 + 8)) ^ xsw)) = hv[j * 2 + 1];
    }
    *(u64*)(lb + (int)((1024u + sch * 8) ^ xsw)) = vy;
  }

  // 8: close the half: LDS visible, publish store drained, then flag X
  asm volatile("s_waitcnt vmcnt(0) lgkmcnt(0)" ::: "memory");
  __builtin_amdgcn_sched_barrier(0);
  __builtin_amdgcn_s_barrier();
  if (pub && tid == 0) {
    unsigned sv = (unsigned)(s + 1);
    asm volatile("global_store_dword %0, %1, off sc0 sc1" :: "v"(flagX), "v"(sv) : "memory");
  }
}

// ---------------- recurrent LSTM, 2-group interleaved, weight-stationary -----
__global__ __launch_bounds__(256, 1) void lstm_rec(
    const short* __restrict__ yw,      // [256][1024][64] bf16
    const float* __restrict__ w_hh,    // [2048][512]
    const float* __restrict__ w_ih,    // [2048][64]
    const float* __restrict__ b_ih, const float* __restrict__ b_hh,
    short* hbuf,                       // [2][1024][512] bf16
    float* __restrict__ hfinal,        // [1024][512]
    unsigned* ctr)                     // flags at u32[1024 + (g*8+gn)*16]
{
  __shared__ __align__(16) char Ash[82432];   // >81920 -> exactly 1 WG/CU
  const int tid = threadIdx.x;
  const int wg  = blockIdx.x;
  const int gn  = wg & 7;              // 64-col slice
  const int gp  = wg >> 3;             // pod 0..31
  const int gA  = gp, gB = gp + 32;
  const int wv  = tid >> 6;
  const int lane = tid & 63;
  const int l15 = lane & 15;
  const int l4  = lane >> 4;

  // ---- resident weights: 4 gates x 18 kt, cols gn*64 + wv*16 + l15 ----
  bx8 Bf[4 * NKT];
  float bias[4];
  const int colh = gn * 64 + wv * 16 + l15;
#pragma unroll
  for (int nt = 0; nt < 4; ++nt) {
    const int col = nt * 512 + colh;
    bias[nt] = b_ih[col] + b_hh[col];
#pragma unroll
    for (int kt = 0; kt < NKT; ++kt) {
      const int k0 = kt * 32 + l4 * 8;
      const float* src = (k0 < 512) ? (w_hh + (size_t)col * 512 + k0)
                                    : (w_ih + (size_t)col * 64 + (k0 - 512));
      fx4 w0 = *(const fx4*)(src);
      fx4 w1 = *(const fx4*)(src + 4);
      bx8 b;
#pragma unroll
      for (int t = 0; t < 4; ++t) { b[t] = bf16_of(w0[t]); b[4 + t] = bf16_of(w1[t]); }
      Bf[nt * NKT + kt] = b;
    }
  }

  float cstA[4], cstB[4];
#pragma unroll
  for (int i = 0; i < 4; ++i) { cstA[i] = 0.f; cstB[i] = 0.f; }

  const int srow = tid >> 4;           // 0..15: staging/publish row
  const int sch  = tid & 15;
  const unsigned xsw = (unsigned)((srow & 7) << 4);
  const unsigned xm  = (unsigned)((l15 & 7) << 4);
  char* trpA = Ash + TRPO;
  char* trpB = Ash + TRPO + 2048;

  unsigned* flbase = ctr + 1024;
  unsigned* flagA = flbase + (gA * 8 + gn) * 16;
  unsigned* flagB = flbase + (gB * 8 + gn) * 16;
  const unsigned* pollA = flbase + (gA * 8 + (lane & 7)) * 16;
  const unsigned* pollB = flbase + (gB * 8 + (lane & 7)) * 16;

  // ---- prologue: stage A(0) (h=0 from memset; plain compiler-tracked loads) --
  {
    u64 vy = *(const u64*)((const char*)(yw + (size_t)255 * 65536) +
                           (size_t)(gA * 16 + srow) * 128 + sch * 8);
    const u64* hq = (const u64*)((const char*)hbuf + (size_t)(gA * 16 + srow) * 1024) + sch * 2;
    char* lb = Ash + srow * ROWB;
#pragma unroll
    for (int j = 0; j < 4; ++j) {
      u64 a = hq[j * 32], b = hq[j * 32 + 1];
      *(u64*)(lb + (int)(((unsigned)(sch * 16 + j * 256))     ^ xsw)) = a;
      *(u64*)(lb + (int)(((unsigned)(sch * 16 + j * 256 + 8)) ^ xsw)) = b;
    }
    *(u64*)(lb + (int)((1024u + sch * 8) ^ xsw)) = vy;
    asm volatile("s_waitcnt lgkmcnt(0)" ::: "memory");
    __builtin_amdgcn_sched_barrier(0);
    __builtin_amdgcn_s_barrier();
  }

#pragma unroll 1
  for (int s = 0; s < NSTEP; ++s) {
    const char* hp = (const char*)hbuf + (size_t)(s & 1) * 1048576;
    char* hn = (char*)hbuf + (size_t)((s + 1) & 1) * 1048576;
    const short* ysl  = yw + (size_t)(255 - s) * 65536;
    const short* yslN = yw + (size_t)(s < 255 ? 254 - s : 0) * 65536;
    const bool pub = (s < 255);
    // half A: compute A(s) -> h_A(s+1); prefetch B(s) from hp
    do_half(s, pub, true, gA, gB, Ash, 0, GREG, trpA, Bf, bias, cstA,
            ysl, hp, hn, hfinal, flagA, pollB, (unsigned)s,
            tid, wv, l15, l4, srow, sch, xsw, xm, colh, gn);
    // half B: compute B(s) -> h_B(s+1); prefetch A(s+1) from hn
    do_half(s, pub, pub, gB, gA, Ash, GREG, 0, trpB, Bf, bias, cstB,
            yslN, hn, hn, hfinal, flagB, pollA, (unsigned)(s + 1),
            tid, wv, l15, l4, srow, sch, xsw, xm, colh, gn);
  }
}

// ---------------- heads: exact fp32 VALU GEMM [1024 x 324 x 512] + epilogue --
__global__ __launch_bounds__(256) void heads_kernel(
    const float* __restrict__ hf,
    const float* __restrict__ lin_w, const float* __restrict__ lin_b,
    const float* __restrict__ lv_w,  const float* __restrict__ lv_b,
    const float* __restrict__ u_w,   const float* __restrict__ u_b,
    const float* __restrict__ ww_w,  const float* __restrict__ ww_b,
    const float* __restrict__ bf_w,  const float* __restrict__ bf_b,
    float* __restrict__ out)
{
  __shared__ float hs[64 * 513];
  const int tid = threadIdx.x;
  const int gb = blockIdx.x;     // 0..15
  const int cg = blockIdx.y;     // 0..5, 54 cols each
  for (int i = tid; i < 8192; i += 256) {
    fx4 v = *(const fx4*)(hf + (size_t)gb * 32768 + (size_t)i * 4);
    const int row = i >> 7;
    const int k = (i * 4) & 511;
    float* d = hs + row * 513 + k;
    d[0] = v[0]; d[1] = v[1]; d[2] = v[2]; d[3] = v[3];
  }
  __syncthreads();
  const int r = tid & 63;
  const int cq = tid >> 6;
  const float* hrow = hs + r * 513;
  const int b_ = gb * 64 + r;
#pragma unroll 1
  for (int j = 0; j < 14; ++j) {
    const int cl = cq + 4 * j;
    if (cl >= 54) break;
    const int C = cg * 54 + cl;      // 0..323
    const float* wp; float bv;
    if (C < 32)       { wp = lin_w + (size_t)C * 512;        bv = lin_b[C]; }
    else if (C < 64)  { wp = lv_w + (size_t)(C - 32) * 512;  bv = lv_b[C - 32]; }
    else if (C < 192) { wp = u_w + (size_t)(C - 64) * 512;   bv = u_b[C - 64]; }
    else if (C < 320) { wp = ww_w + (size_t)(C - 192) * 512; bv = ww_b[C - 192]; }
    else              { wp = bf_w + (size_t)(C - 320) * 512; bv = bf_b[C - 320]; }
    float dot = 0.f;
#pragma unroll 8
    for (int k = 0; k < 512; k += 4) {
      fx4 w = *(const fx4*)(wp + k);
      dot += hrow[k] * w[0] + hrow[k + 1] * w[1] + hrow[k + 2] * w[2] + hrow[k + 3] * w[3];
    }
    const float res = bv + dot;
    if (C < 32)       out[(size_t)b_ * 32 + C] = __builtin_amdgcn_exp2f(res * 1.44269504f) * 0.1f;
    else if (C < 64)  out[32768 + (size_t)b_ * 32 + (C - 32)] = res - 5.f;
    else if (C < 192) out[65536 + (size_t)b_ * 128 + (C - 64)] = res;
    else if (C < 320) out[196608 + (size_t)b_ * 128 + (C - 192)] = res;
    else              out[327680 + (size_t)b_ * 4 + (C - 320)] = res;
  }
}

extern "C" void kernel_launch(void* const* d_in, const int* in_sizes, int n_in,
                              void* d_out, int out_size, void* d_ws, size_t ws_size,
                              hipStream_t stream) {
  (void)in_sizes; (void)n_in; (void)out_size; (void)ws_size;
  const float* x     = (const float*)d_in[0];
  const float* a     = (const float*)d_in[1];
  const float* mask  = (const float*)d_in[2];
  const float* w_ih  = (const float*)d_in[3];
  const float* w_hh  = (const float*)d_in[4];
  const float* b_ih  = (const float*)d_in[5];
  const float* b_hh  = (const float*)d_in[6];
  const float* lin_w = (const float*)d_in[7];
  const float* lin_b = (const float*)d_in[8];
  const float* lv_w  = (const float*)d_in[9];
  const float* lv_b  = (const float*)d_in[10];
  const float* u_w   = (const float*)d_in[11];
  const float* u_b   = (const float*)d_in[12];
  const float* ww_w  = (const float*)d_in[13];
  const float* ww_b  = (const float*)d_in[14];
  const float* bf_w  = (const float*)d_in[15];
  const float* bf_b  = (const float*)d_in[16];

  char* ws = (char*)d_ws;
  short* yw       = (short*)(ws);                 // 33,554,432 B: [256][1024][64] bf16
  short* hbuf     = (short*)(ws + 33554432);      //  2,097,152 B: [2][1024][512] bf16
  float* hfinal   = (float*)(ws + 35651584);      //  2,097,152 B
  unsigned* ctr   = (unsigned*)(ws + 37748736);   //     36,864 B (flags region)

  hipMemsetAsync(hbuf, 0, 2097152, stream);       // both slots -> finite residue
  hipMemsetAsync(ctr, 0, 36864, stream);

  pack_y_kernel<<<1024, 256, 0, stream>>>(x, a, mask, yw);
  lstm_rec<<<256, 256, 0, stream>>>(yw, w_hh, w_ih, b_ih, b_hh, hbuf, hfinal, ctr);
  heads_kernel<<<dim3(16, 6), 256, 0, stream>>>(hfinal, lin_w, lin_b, lv_w, lv_b,
                                                u_w, u_b, ww_w, ww_b, bf_w, bf_b,
                                                (float*)d_out);
}

// Round 9
// 1490.085 us; speedup vs baseline: 1.0774x; 1.0774x over previous
//
#include <hip/hip_runtime.h>

// EncoderPlanarLSTM: T=256,B=1024,DX=48,DA=16 (I=64), H=512, Z=32, F=4
// out = [mu(1024x32) | log_var(1024x32) | u(1024x128) | w(1024x128) | b(1024x4)] fp32
//
// R9: 2-group interleave with MALL-local asm loads (sc0 sc1, R6-proven FETCH) and
// reordered half so RTTs overlap compute: MFMA -> gates -> trp-write -> poll(all waves)
// -> issue h+y loads -> barrier -> publish store (ack overlaps loads) -> stage -> drain.

typedef __attribute__((__ext_vector_type__(8))) short bx8;   // 8 bf16 (4 VGPR)
typedef __attribute__((__ext_vector_type__(4))) float fx4;
typedef __attribute__((__ext_vector_type__(4))) unsigned ux4;
typedef unsigned long long u64;

#define NSTEP 256
#define NKT   18          // K-tiles of 32 over K=576 (512 h + 64 y)
#define ROWB  1184        // LDS bytes per A row (1152 data + 32 pad)
#define GREG  18944       // per-group LDS region: 16 rows * 1184
#define TRPO  37888       // transpose slabs at 2*GREG

__device__ __forceinline__ short bf16_of(float f) {
  union { float f; unsigned u; } c; c.f = f;
  unsigned r = c.u + 0x7fffu + ((c.u >> 16) & 1u);   // RNE
  return (short)(r >> 16);
}
__device__ __forceinline__ float fsigmoid(float x) {
  float e = __builtin_amdgcn_exp2f(-1.44269504f * x);
  return __builtin_amdgcn_rcpf(1.0f + e);
}
__device__ __forceinline__ float ftanh_(float x) {
  float e = __builtin_amdgcn_exp2f(2.88539008f * x);
  return 1.0f - 2.0f * __builtin_amdgcn_rcpf(1.0f + e);
}

__device__ __forceinline__ void poll_flags(const unsigned* p, unsigned tgt) {
  unsigned guard = 0;
  for (;;) {
    unsigned v;
    asm volatile("global_load_dword %0, %1, off sc0 sc1\n\ts_waitcnt vmcnt(0)"
                 : "=v"(v) : "v"(p) : "memory");
    if (__all((int)(v >= tgt))) break;
    if (++guard > (1u << 18)) break;      // bail: terminate, never hang
    __builtin_amdgcn_s_sleep(1);
  }
}

// ---------------- pack masked+concat input to bf16, natural time order -------
__global__ __launch_bounds__(256) void pack_y_kernel(
    const float* __restrict__ x, const float* __restrict__ a,
    const float* __restrict__ mk, short* __restrict__ y) {
  const int idx = blockIdx.x * 256 + threadIdx.x;
  const float* xp = x + (size_t)idx * 48;
  const float* mp = mk + (size_t)idx * 48;
  const float* ap = a + (size_t)idx * 16;
  short* yp = y + (size_t)idx * 64;
  float v[64];
#pragma unroll
  for (int j = 0; j < 12; ++j) {
    fx4 xv = *(const fx4*)(xp + j * 4);
    fx4 mv = *(const fx4*)(mp + j * 4);
#pragma unroll
    for (int t = 0; t < 4; ++t) v[j * 4 + t] = xv[t] * mv[t];
  }
#pragma unroll
  for (int j = 0; j < 4; ++j) {
    fx4 av = *(const fx4*)(ap + j * 4);
#pragma unroll
    for (int t = 0; t < 4; ++t) v[48 + j * 4 + t] = av[t];
  }
#pragma unroll
  for (int c = 0; c < 8; ++c) {
    bx8 o;
#pragma unroll
    for (int t = 0; t < 8; ++t) o[t] = bf16_of(v[c * 8 + t]);
    *(bx8*)(yp + c * 8) = o;
  }
}

// ---------------- one half-iteration: compute group X, prefetch group Y ------
__device__ __forceinline__ void do_half(
    int s, bool pub, bool pref,
    int gX, int gY, char* Ash, int regX, int regY, char* trpX,
    const bx8* Bf, const float* bias, float* cstX,
    const short* yslY, const char* hprevY, char* hnextX,
    float* __restrict__ hfinal, unsigned* flagX, const unsigned* pollY, unsigned tgtY,
    int tid, int wv, int l15, int l4, int srow, int sch,
    unsigned xsw, unsigned xm, int colh, int gn)
{
  // 1: MFMA X (A staged in LDS during the previous half)
  fx4 acc[4];
#pragma unroll
  for (int nt = 0; nt < 4; ++nt) {
    fx4 z = {bias[nt], bias[nt], bias[nt], bias[nt]};
    acc[nt] = z;
  }
  const char* abase = Ash + regX + l15 * ROWB;
  const unsigned kbase = (unsigned)(l4 * 16);
#pragma unroll
  for (int kt = 0; kt < NKT; ++kt) {
    bx8 A0 = *(const bx8*)(abase + (int)(((unsigned)(kt * 64) + kbase) ^ xm));
#pragma unroll
    for (int nt = 0; nt < 4; ++nt)
      acc[nt] = __builtin_amdgcn_mfma_f32_16x16x32_bf16(A0, Bf[nt * NKT + kt], acc[nt], 0, 0, 0);
  }

  // 2: gates + state update
  unsigned hs16[4];
#pragma unroll
  for (int r = 0; r < 4; ++r) {
    float gi = acc[0][r], gf = acc[1][r], gg = acc[2][r], go = acc[3][r];
    float c = fsigmoid(gf) * cstX[r] + fsigmoid(gi) * ftanh_(gg);
    cstX[r] = c;
    float h = fsigmoid(go) * ftanh_(c);
    hs16[r] = (unsigned)(unsigned short)bf16_of(h);
    if (!pub) hfinal[(size_t)(gX * 16 + l4 * 4 + r) * 512 + colh] = h;
  }

  // 3: trp-write X (LDS transpose for coalesced publish)
  if (pub) {
#pragma unroll
    for (int r = 0; r < 4; ++r)
      *(unsigned short*)(trpX + (l4 * 4 + r) * 128 + (wv * 16 + l15) * 2) =
          (unsigned short)hs16[r];
    asm volatile("s_waitcnt lgkmcnt(0)" ::: "memory");
    __builtin_amdgcn_sched_barrier(0);
  }

  // 4: poll Y flags — ALL waves poll (no barrier between poll and load issue)
  if (pref) poll_flags(pollY, tgtY);

  // 5: issue Y h-loads (MALL-local sc0 sc1) + y-load. Short liveness window:
  //    consumed right after the barrier + vmcnt — no spin in between (R7 lesson).
  ux4 vh0, vh1, vh2, vh3; u64 vy;
  if (pref) {
    const char* hq = hprevY + (size_t)(gY * 16 + srow) * 1024 + sch * 16;
    asm volatile("global_load_dwordx4 %0, %1, off sc0 sc1" : "=v"(vh0) : "v"(hq) : "memory");
    asm volatile("global_load_dwordx4 %0, %1, off offset:256 sc0 sc1" : "=v"(vh1) : "v"(hq) : "memory");
    asm volatile("global_load_dwordx4 %0, %1, off offset:512 sc0 sc1" : "=v"(vh2) : "v"(hq) : "memory");
    asm volatile("global_load_dwordx4 %0, %1, off offset:768 sc0 sc1" : "=v"(vh3) : "v"(hq) : "memory");
    const char* yp = (const char*)yslY + (size_t)(gY * 16 + srow) * 128 + sch * 8;
    asm volatile("global_load_dwordx2 %0, %1, off" : "=v"(vy) : "v"(yp) : "memory");
  }

  // 6: barrier — trp visible to all; every wave has passed its poll
  __builtin_amdgcn_s_barrier();

  // 7: publish store issued AFTER the loads -> its ack overlaps their RTT
  if (pub) {
    u64 pv = *(const u64*)(trpX + srow * 128 + sch * 8);
    char* sb = hnextX + (size_t)(gX * 16 + srow) * 1024 + gn * 128 + sch * 8;
    asm volatile("global_store_dwordx2 %0, %1, off sc0 sc1" :: "v"(sb), "v"(pv) : "memory");
  }

  // 8: wait loads only (store may stay outstanding), stage Y into LDS
  if (pref) {
    if (pub) asm volatile("s_waitcnt vmcnt(1)" ::: "memory");
    else     asm volatile("s_waitcnt vmcnt(0)" ::: "memory");
    __builtin_amdgcn_sched_barrier(0);
    char* lb = Ash + regY + srow * ROWB;
    *(ux4*)(lb + (int)(((unsigned)(sch * 16 + 0))   ^ xsw)) = vh0;
    *(ux4*)(lb + (int)(((unsigned)(sch * 16 + 256)) ^ xsw)) = vh1;
    *(ux4*)(lb + (int)(((unsigned)(sch * 16 + 512)) ^ xsw)) = vh2;
    *(ux4*)(lb + (int)(((unsigned)(sch * 16 + 768)) ^ xsw)) = vh3;
    *(u64*)(lb + (int)((1024u + sch * 8) ^ xsw)) = vy;
  }

  // 9: close the half: LDS visible, publish store acked, then flag X
  asm volatile("s_waitcnt vmcnt(0) lgkmcnt(0)" ::: "memory");
  __builtin_amdgcn_sched_barrier(0);
  __builtin_amdgcn_s_barrier();
  if (pub && tid == 0) {
    unsigned sv = (unsigned)(s + 1);
    asm volatile("global_store_dword %0, %1, off sc0 sc1" :: "v"(flagX), "v"(sv) : "memory");
  }
}

// ---------------- recurrent LSTM, 2-group interleaved, weight-stationary -----
__global__ __launch_bounds__(256, 1) void lstm_rec(
    const short* __restrict__ yw,      // [256][1024][64] bf16
    const float* __restrict__ w_hh,    // [2048][512]
    const float* __restrict__ w_ih,    // [2048][64]
    const float* __restrict__ b_ih, const float* __restrict__ b_hh,
    short* hbuf,                       // [2][1024][512] bf16
    float* __restrict__ hfinal,        // [1024][512]
    unsigned* ctr)                     // flags at u32[1024 + (g*8+gn)*16]
{
  __shared__ __align__(16) char Ash[82432];   // >81920 -> exactly 1 WG/CU
  const int tid = threadIdx.x;
  const int wg  = blockIdx.x;
  const int gn  = wg & 7;              // 64-col slice
  const int gp  = wg >> 3;             // pod 0..31
  const int gA  = gp, gB = gp + 32;
  const int wv  = tid >> 6;
  const int lane = tid & 63;
  const int l15 = lane & 15;
  const int l4  = lane >> 4;

  // ---- resident weights: 4 gates x 18 kt, cols gn*64 + wv*16 + l15 ----
  bx8 Bf[4 * NKT];
  float bias[4];
  const int colh = gn * 64 + wv * 16 + l15;
#pragma unroll
  for (int nt = 0; nt < 4; ++nt) {
    const int col = nt * 512 + colh;
    bias[nt] = b_ih[col] + b_hh[col];
#pragma unroll
    for (int kt = 0; kt < NKT; ++kt) {
      const int k0 = kt * 32 + l4 * 8;
      const float* src = (k0 < 512) ? (w_hh + (size_t)col * 512 + k0)
                                    : (w_ih + (size_t)col * 64 + (k0 - 512));
      fx4 w0 = *(const fx4*)(src);
      fx4 w1 = *(const fx4*)(src + 4);
      bx8 b;
#pragma unroll
      for (int t = 0; t < 4; ++t) { b[t] = bf16_of(w0[t]); b[4 + t] = bf16_of(w1[t]); }
      Bf[nt * NKT + kt] = b;
    }
  }

  float cstA[4], cstB[4];
#pragma unroll
  for (int i = 0; i < 4; ++i) { cstA[i] = 0.f; cstB[i] = 0.f; }

  const int srow = tid >> 4;           // 0..15: staging/publish row
  const int sch  = tid & 15;
  const unsigned xsw = (unsigned)((srow & 7) << 4);
  const unsigned xm  = (unsigned)((l15 & 7) << 4);
  char* trpA = Ash + TRPO;
  char* trpB = Ash + TRPO + 2048;

  unsigned* flbase = ctr + 1024;
  unsigned* flagA = flbase + (gA * 8 + gn) * 16;
  unsigned* flagB = flbase + (gB * 8 + gn) * 16;
  const unsigned* pollA = flbase + (gA * 8 + (lane & 7)) * 16;
  const unsigned* pollB = flbase + (gB * 8 + (lane & 7)) * 16;

  // ---- prologue: stage A(0) (h=0 from memset; plain compiler-tracked loads) --
  {
    u64 vy = *(const u64*)((const char*)(yw + (size_t)255 * 65536) +
                           (size_t)(gA * 16 + srow) * 128 + sch * 8);
    const u64* hq = (const u64*)((const char*)hbuf + (size_t)(gA * 16 + srow) * 1024) + sch * 2;
    char* lb = Ash + srow * ROWB;
#pragma unroll
    for (int j = 0; j < 4; ++j) {
      u64 a = hq[j * 32], b = hq[j * 32 + 1];
      *(u64*)(lb + (int)(((unsigned)(sch * 16 + j * 256))     ^ xsw)) = a;
      *(u64*)(lb + (int)(((unsigned)(sch * 16 + j * 256 + 8)) ^ xsw)) = b;
    }
    *(u64*)(lb + (int)((1024u + sch * 8) ^ xsw)) = vy;
    asm volatile("s_waitcnt lgkmcnt(0)" ::: "memory");
    __builtin_amdgcn_sched_barrier(0);
    __builtin_amdgcn_s_barrier();
  }

#pragma unroll 1
  for (int s = 0; s < NSTEP; ++s) {
    const char* hp = (const char*)hbuf + (size_t)(s & 1) * 1048576;
    char* hn = (char*)hbuf + (size_t)((s + 1) & 1) * 1048576;
    const short* ysl  = yw + (size_t)(255 - s) * 65536;
    const short* yslN = yw + (size_t)(s < 255 ? 254 - s : 0) * 65536;
    const bool pub = (s < 255);
    // half A: compute A(s) -> h_A(s+1); prefetch B(s) from hp
    do_half(s, pub, true, gA, gB, Ash, 0, GREG, trpA, Bf, bias, cstA,
            ysl, hp, hn, hfinal, flagA, pollB, (unsigned)s,
            tid, wv, l15, l4, srow, sch, xsw, xm, colh, gn);
    // half B: compute B(s) -> h_B(s+1); prefetch A(s+1) from hn
    do_half(s, pub, pub, gB, gA, Ash, GREG, 0, trpB, Bf, bias, cstB,
            yslN, hn, hn, hfinal, flagB, pollA, (unsigned)(s + 1),
            tid, wv, l15, l4, srow, sch, xsw, xm, colh, gn);
  }
}

// ---------------- heads: exact fp32 VALU GEMM [1024 x 324 x 512] + epilogue --
__global__ __launch_bounds__(256) void heads_kernel(
    const float* __restrict__ hf,
    const float* __restrict__ lin_w, const float* __restrict__ lin_b,
    const float* __restrict__ lv_w,  const float* __restrict__ lv_b,
    const float* __restrict__ u_w,   const float* __restrict__ u_b,
    const float* __restrict__ ww_w,  const float* __restrict__ ww_b,
    const float* __restrict__ bf_w,  const float* __restrict__ bf_b,
    float* __restrict__ out)
{
  __shared__ float hs[64 * 513];
  const int tid = threadIdx.x;
  const int gb = blockIdx.x;     // 0..15
  const int cg = blockIdx.y;     // 0..5, 54 cols each
  for (int i = tid; i < 8192; i += 256) {
    fx4 v = *(const fx4*)(hf + (size_t)gb * 32768 + (size_t)i * 4);
    const int row = i >> 7;
    const int k = (i * 4) & 511;
    float* d = hs + row * 513 + k;
    d[0] = v[0]; d[1] = v[1]; d[2] = v[2]; d[3] = v[3];
  }
  __syncthreads();
  const int r = tid & 63;
  const int cq = tid >> 6;
  const float* hrow = hs + r * 513;
  const int b_ = gb * 64 + r;
#pragma unroll 1
  for (int j = 0; j < 14; ++j) {
    const int cl = cq + 4 * j;
    if (cl >= 54) break;
    const int C = cg * 54 + cl;      // 0..323
    const float* wp; float bv;
    if (C < 32)       { wp = lin_w + (size_t)C * 512;        bv = lin_b[C]; }
    else if (C < 64)  { wp = lv_w + (size_t)(C - 32) * 512;  bv = lv_b[C - 32]; }
    else if (C < 192) { wp = u_w + (size_t)(C - 64) * 512;   bv = u_b[C - 64]; }
    else if (C < 320) { wp = ww_w + (size_t)(C - 192) * 512; bv = ww_b[C - 192]; }
    else              { wp = bf_w + (size_t)(C - 320) * 512; bv = bf_b[C - 320]; }
    float dot = 0.f;
#pragma unroll 8
    for (int k = 0; k < 512; k += 4) {
      fx4 w = *(const fx4*)(wp + k);
      dot += hrow[k] * w[0] + hrow[k + 1] * w[1] + hrow[k + 2] * w[2] + hrow[k + 3] * w[3];
    }
    const float res = bv + dot;
    if (C < 32)       out[(size_t)b_ * 32 + C] = __builtin_amdgcn_exp2f(res * 1.44269504f) * 0.1f;
    else if (C < 64)  out[32768 + (size_t)b_ * 32 + (C - 32)] = res - 5.f;
    else if (C < 192) out[65536 + (size_t)b_ * 128 + (C - 64)] = res;
    else if (C < 320) out[196608 + (size_t)b_ * 128 + (C - 192)] = res;
    else              out[327680 + (size_t)b_ * 4 + (C - 320)] = res;
  }
}

extern "C" void kernel_launch(void* const* d_in, const int* in_sizes, int n_in,
                              void* d_out, int out_size, void* d_ws, size_t ws_size,
                              hipStream_t stream) {
  (void)in_sizes; (void)n_in; (void)out_size; (void)ws_size;
  const float* x     = (const float*)d_in[0];
  const float* a     = (const float*)d_in[1];
  const float* mask  = (const float*)d_in[2];
  const float* w_ih  = (const float*)d_in[3];
  const float* w_hh  = (const float*)d_in[4];
  const float* b_ih  = (const float*)d_in[5];
  const float* b_hh  = (const float*)d_in[6];
  const float* lin_w = (const float*)d_in[7];
  const float* lin_b = (const float*)d_in[8];
  const float* lv_w  = (const float*)d_in[9];
  const float* lv_b  = (const float*)d_in[10];
  const float* u_w   = (const float*)d_in[11];
  const float* u_b   = (const float*)d_in[12];
  const float* ww_w  = (const float*)d_in[13];
  const float* ww_b  = (const float*)d_in[14];
  const float* bf_w  = (const float*)d_in[15];
  const float* bf_b  = (const float*)d_in[16];

  char* ws = (char*)d_ws;
  short* yw       = (short*)(ws);                 // 33,554,432 B: [256][1024][64] bf16
  short* hbuf     = (short*)(ws + 33554432);      //  2,097,152 B: [2][1024][512] bf16
  float* hfinal   = (float*)(ws + 35651584);      //  2,097,152 B
  unsigned* ctr   = (unsigned*)(ws + 37748736);   //     36,864 B (flags region)

  hipMemsetAsync(hbuf, 0, 2097152, stream);       // both slots -> finite residue
  hipMemsetAsync(ctr, 0, 36864, stream);

  pack_y_kernel<<<1024, 256, 0, stream>>>(x, a, mask, yw);
  lstm_rec<<<256, 256, 0, stream>>>(yw, w_hh, w_ih, b_ih, b_hh, hbuf, hfinal, ctr);
  heads_kernel<<<dim3(16, 6), 256, 0, stream>>>(hfinal, lin_w, lin_b, lv_w, lv_b,
                                                u_w, u_b, ww_w, ww_b, bf_w, bf_b,
                                                (float*)d_out);
}

// Round 10
// 1409.926 us; speedup vs baseline: 1.1387x; 1.0569x over previous
//
#include <hip/hip_runtime.h>

// EncoderPlanarLSTM: T=256,B=1024,DX=48,DA=16 (I=64), H=512, Z=32, F=4
// out = [mu(1024x32) | log_var(1024x32) | u(1024x128) | w(1024x128) | b(1024x4)] fp32
//
// R10: R9 pipeline with XCD-local group mapping. 64 groups x 16 batch rows;
// group g's 8 col-slice WGs are wg = (g>>2) % 8 + 64*(g&3) + 8*gn  -> all share
// one XCD under round-robin xcd = wg%8 (validated empirically by R6's FETCH).
// h + flags exchange through that XCD's L2 (sc0 sc1 write-through, sc0 sc1 loads
// hit local L2 when present). Mapping is perf-only: protocol is cross-XCD correct.

typedef __attribute__((__ext_vector_type__(8))) short bx8;   // 8 bf16 (4 VGPR)
typedef __attribute__((__ext_vector_type__(4))) float fx4;
typedef __attribute__((__ext_vector_type__(4))) unsigned ux4;
typedef unsigned long long u64;

#define NSTEP 256
#define NKT   18          // K-tiles of 32 over K=576 (512 h + 64 y)
#define ROWB  1184        // LDS bytes per A row (1152 data + 32 pad)
#define GREG  18944       // per-group LDS region: 16 rows * 1184
#define TRPO  37888       // transpose slabs at 2*GREG

__device__ __forceinline__ short bf16_of(float f) {
  union { float f; unsigned u; } c; c.f = f;
  unsigned r = c.u + 0x7fffu + ((c.u >> 16) & 1u);   // RNE
  return (short)(r >> 16);
}
__device__ __forceinline__ float fsigmoid(float x) {
  float e = __builtin_amdgcn_exp2f(-1.44269504f * x);
  return __builtin_amdgcn_rcpf(1.0f + e);
}
__device__ __forceinline__ float ftanh_(float x) {
  float e = __builtin_amdgcn_exp2f(2.88539008f * x);
  return 1.0f - 2.0f * __builtin_amdgcn_rcpf(1.0f + e);
}

__device__ __forceinline__ void poll_flags(const unsigned* p, unsigned tgt) {
  unsigned guard = 0;
  for (;;) {
    unsigned v;
    asm volatile("global_load_dword %0, %1, off sc0 sc1\n\ts_waitcnt vmcnt(0)"
                 : "=v"(v) : "v"(p) : "memory");
    if (__all((int)(v >= tgt))) break;
    if (++guard > (1u << 18)) break;      // bail: terminate, never hang
    __builtin_amdgcn_s_sleep(1);
  }
}

// ---------------- pack masked+concat input to bf16, natural time order -------
__global__ __launch_bounds__(256) void pack_y_kernel(
    const float* __restrict__ x, const float* __restrict__ a,
    const float* __restrict__ mk, short* __restrict__ y) {
  const int idx = blockIdx.x * 256 + threadIdx.x;
  const float* xp = x + (size_t)idx * 48;
  const float* mp = mk + (size_t)idx * 48;
  const float* ap = a + (size_t)idx * 16;
  short* yp = y + (size_t)idx * 64;
  float v[64];
#pragma unroll
  for (int j = 0; j < 12; ++j) {
    fx4 xv = *(const fx4*)(xp + j * 4);
    fx4 mv = *(const fx4*)(mp + j * 4);
#pragma unroll
    for (int t = 0; t < 4; ++t) v[j * 4 + t] = xv[t] * mv[t];
  }
#pragma unroll
  for (int j = 0; j < 4; ++j) {
    fx4 av = *(const fx4*)(ap + j * 4);
#pragma unroll
    for (int t = 0; t < 4; ++t) v[48 + j * 4 + t] = av[t];
  }
#pragma unroll
  for (int c = 0; c < 8; ++c) {
    bx8 o;
#pragma unroll
    for (int t = 0; t < 8; ++t) o[t] = bf16_of(v[c * 8 + t]);
    *(bx8*)(yp + c * 8) = o;
  }
}

// ---------------- one half-iteration: compute group X, prefetch group Y ------
__device__ __forceinline__ void do_half(
    int s, bool pub, bool pref,
    int gX, int gY, char* Ash, int regX, int regY, char* trpX,
    const bx8* Bf, const float* bias, float* cstX,
    const short* yslY, const char* hprevY, char* hnextX,
    float* __restrict__ hfinal, unsigned* flagX, const unsigned* pollY, unsigned tgtY,
    int tid, int wv, int l15, int l4, int srow, int sch,
    unsigned xsw, unsigned xm, int colh, int gn)
{
  // 1: MFMA X (A staged in LDS during the previous half)
  fx4 acc[4];
#pragma unroll
  for (int nt = 0; nt < 4; ++nt) {
    fx4 z = {bias[nt], bias[nt], bias[nt], bias[nt]};
    acc[nt] = z;
  }
  const char* abase = Ash + regX + l15 * ROWB;
  const unsigned kbase = (unsigned)(l4 * 16);
#pragma unroll
  for (int kt = 0; kt < NKT; ++kt) {
    bx8 A0 = *(const bx8*)(abase + (int)(((unsigned)(kt * 64) + kbase) ^ xm));
#pragma unroll
    for (int nt = 0; nt < 4; ++nt)
      acc[nt] = __builtin_amdgcn_mfma_f32_16x16x32_bf16(A0, Bf[nt * NKT + kt], acc[nt], 0, 0, 0);
  }

  // 2: gates + state update
  unsigned hs16[4];
#pragma unroll
  for (int r = 0; r < 4; ++r) {
    float gi = acc[0][r], gf = acc[1][r], gg = acc[2][r], go = acc[3][r];
    float c = fsigmoid(gf) * cstX[r] + fsigmoid(gi) * ftanh_(gg);
    cstX[r] = c;
    float h = fsigmoid(go) * ftanh_(c);
    hs16[r] = (unsigned)(unsigned short)bf16_of(h);
    if (!pub) hfinal[(size_t)(gX * 16 + l4 * 4 + r) * 512 + colh] = h;
  }

  // 3: trp-write X (LDS transpose for coalesced publish)
  if (pub) {
#pragma unroll
    for (int r = 0; r < 4; ++r)
      *(unsigned short*)(trpX + (l4 * 4 + r) * 128 + (wv * 16 + l15) * 2) =
          (unsigned short)hs16[r];
    asm volatile("s_waitcnt lgkmcnt(0)" ::: "memory");
    __builtin_amdgcn_sched_barrier(0);
  }

  // 4: poll Y flags — ALL waves poll (no barrier between poll and load issue)
  if (pref) poll_flags(pollY, tgtY);

  // 5: issue Y h-loads (XCD-L2-local sc0 sc1) + y-load. Short liveness window:
  //    consumed right after the barrier + vmcnt — no spin in between (R7 lesson).
  ux4 vh0, vh1, vh2, vh3; u64 vy;
  if (pref) {
    const char* hq = hprevY + (size_t)(gY * 16 + srow) * 1024 + sch * 16;
    asm volatile("global_load_dwordx4 %0, %1, off sc0 sc1" : "=v"(vh0) : "v"(hq) : "memory");
    asm volatile("global_load_dwordx4 %0, %1, off offset:256 sc0 sc1" : "=v"(vh1) : "v"(hq) : "memory");
    asm volatile("global_load_dwordx4 %0, %1, off offset:512 sc0 sc1" : "=v"(vh2) : "v"(hq) : "memory");
    asm volatile("global_load_dwordx4 %0, %1, off offset:768 sc0 sc1" : "=v"(vh3) : "v"(hq) : "memory");
    const char* yp = (const char*)yslY + (size_t)(gY * 16 + srow) * 128 + sch * 8;
    asm volatile("global_load_dwordx2 %0, %1, off" : "=v"(vy) : "v"(yp) : "memory");
  }

  // 6: barrier — trp visible to all; every wave has passed its poll
  __builtin_amdgcn_s_barrier();

  // 7: publish store issued AFTER the loads -> its ack overlaps their RTT
  if (pub) {
    u64 pv = *(const u64*)(trpX + srow * 128 + sch * 8);
    char* sb = hnextX + (size_t)(gX * 16 + srow) * 1024 + gn * 128 + sch * 8;
    asm volatile("global_store_dwordx2 %0, %1, off sc0 sc1" :: "v"(sb), "v"(pv) : "memory");
  }

  // 8: wait loads only (store may stay outstanding), stage Y into LDS
  if (pref) {
    if (pub) asm volatile("s_waitcnt vmcnt(1)" ::: "memory");
    else     asm volatile("s_waitcnt vmcnt(0)" ::: "memory");
    __builtin_amdgcn_sched_barrier(0);
    char* lb = Ash + regY + srow * ROWB;
    *(ux4*)(lb + (int)(((unsigned)(sch * 16 + 0))   ^ xsw)) = vh0;
    *(ux4*)(lb + (int)(((unsigned)(sch * 16 + 256)) ^ xsw)) = vh1;
    *(ux4*)(lb + (int)(((unsigned)(sch * 16 + 512)) ^ xsw)) = vh2;
    *(ux4*)(lb + (int)(((unsigned)(sch * 16 + 768)) ^ xsw)) = vh3;
    *(u64*)(lb + (int)((1024u + sch * 8) ^ xsw)) = vy;
  }

  // 9: close the half: LDS visible, publish store acked, then flag X
  asm volatile("s_waitcnt vmcnt(0) lgkmcnt(0)" ::: "memory");
  __builtin_amdgcn_sched_barrier(0);
  __builtin_amdgcn_s_barrier();
  if (pub && tid == 0) {
    unsigned sv = (unsigned)(s + 1);
    asm volatile("global_store_dword %0, %1, off sc0 sc1" :: "v"(flagX), "v"(sv) : "memory");
  }
}

// ---------------- recurrent LSTM, 2-group interleaved, weight-stationary -----
__global__ __launch_bounds__(256, 1) void lstm_rec(
    const short* __restrict__ yw,      // [256][1024][64] bf16
    const float* __restrict__ w_hh,    // [2048][512]
    const float* __restrict__ w_ih,    // [2048][64]
    const float* __restrict__ b_ih, const float* __restrict__ b_hh,
    short* hbuf,                       // [2][1024][512] bf16
    float* __restrict__ hfinal,        // [1024][512]
    unsigned* ctr)                     // flags at u32[1024 + (g*8+gn)*16]
{
  __shared__ __align__(16) char Ash[82432];   // >81920 -> exactly 1 WG/CU
  const int tid = threadIdx.x;
  const int wg  = blockIdx.x;
  // ---- XCD-local mapping: all 8 slices of a group on one XCD (xcd = wg%8) ----
  const int xcd = wg & 7;
  const int ii  = wg >> 3;             // 0..31 within XCD
  const int gn  = ii & 7;              // 64-col slice
  const int q   = ii >> 3;             // pod 0..3 within XCD
  const int gA  = xcd * 4 + q;         // 0..31
  const int gB  = gA + 32;
  const int wv  = tid >> 6;
  const int lane = tid & 63;
  const int l15 = lane & 15;
  const int l4  = lane >> 4;

  // ---- resident weights: 4 gates x 18 kt, cols gn*64 + wv*16 + l15 ----
  bx8 Bf[4 * NKT];
  float bias[4];
  const int colh = gn * 64 + wv * 16 + l15;
#pragma unroll
  for (int nt = 0; nt < 4; ++nt) {
    const int col = nt * 512 + colh;
    bias[nt] = b_ih[col] + b_hh[col];
#pragma unroll
    for (int kt = 0; kt < NKT; ++kt) {
      const int k0 = kt * 32 + l4 * 8;
      const float* src = (k0 < 512) ? (w_hh + (size_t)col * 512 + k0)
                                    : (w_ih + (size_t)col * 64 + (k0 - 512));
      fx4 w0 = *(const fx4*)(src);
      fx4 w1 = *(const fx4*)(src + 4);
      bx8 b;
#pragma unroll
      for (int t = 0; t < 4; ++t) { b[t] = bf16_of(w0[t]); b[4 + t] = bf16_of(w1[t]); }
      Bf[nt * NKT + kt] = b;
    }
  }

  float cstA[4], cstB[4];
#pragma unroll
  for (int i = 0; i < 4; ++i) { cstA[i] = 0.f; cstB[i] = 0.f; }

  const int srow = tid >> 4;           // 0..15: staging/publish row
  const int sch  = tid & 15;
  const unsigned xsw = (unsigned)((srow & 7) << 4);
  const unsigned xm  = (unsigned)((l15 & 7) << 4);
  char* trpA = Ash + TRPO;
  char* trpB = Ash + TRPO + 2048;

  unsigned* flbase = ctr + 1024;
  unsigned* flagA = flbase + (gA * 8 + gn) * 16;
  unsigned* flagB = flbase + (gB * 8 + gn) * 16;
  const unsigned* pollA = flbase + (gA * 8 + (lane & 7)) * 16;
  const unsigned* pollB = flbase + (gB * 8 + (lane & 7)) * 16;

  // ---- prologue: stage A(0) (h=0 from memset; plain compiler-tracked loads) --
  {
    u64 vy = *(const u64*)((const char*)(yw + (size_t)255 * 65536) +
                           (size_t)(gA * 16 + srow) * 128 + sch * 8);
    const u64* hq = (const u64*)((const char*)hbuf + (size_t)(gA * 16 + srow) * 1024) + sch * 2;
    char* lb = Ash + srow * ROWB;
#pragma unroll
    for (int j = 0; j < 4; ++j) {
      u64 a = hq[j * 32], b = hq[j * 32 + 1];
      *(u64*)(lb + (int)(((unsigned)(sch * 16 + j * 256))     ^ xsw)) = a;
      *(u64*)(lb + (int)(((unsigned)(sch * 16 + j * 256 + 8)) ^ xsw)) = b;
    }
    *(u64*)(lb + (int)((1024u + sch * 8) ^ xsw)) = vy;
    asm volatile("s_waitcnt lgkmcnt(0)" ::: "memory");
    __builtin_amdgcn_sched_barrier(0);
    __builtin_amdgcn_s_barrier();
  }

#pragma unroll 1
  for (int s = 0; s < NSTEP; ++s) {
    const char* hp = (const char*)hbuf + (size_t)(s & 1) * 1048576;
    char* hn = (char*)hbuf + (size_t)((s + 1) & 1) * 1048576;
    const short* ysl  = yw + (size_t)(255 - s) * 65536;
    const short* yslN = yw + (size_t)(s < 255 ? 254 - s : 0) * 65536;
    const bool pub = (s < 255);
    // half A: compute A(s) -> h_A(s+1); prefetch B(s) from hp
    do_half(s, pub, true, gA, gB, Ash, 0, GREG, trpA, Bf, bias, cstA,
            ysl, hp, hn, hfinal, flagA, pollB, (unsigned)s,
            tid, wv, l15, l4, srow, sch, xsw, xm, colh, gn);
    // half B: compute B(s) -> h_B(s+1); prefetch A(s+1) from hn
    do_half(s, pub, pub, gB, gA, Ash, GREG, 0, trpB, Bf, bias, cstB,
            yslN, hn, hn, hfinal, flagB, pollA, (unsigned)(s + 1),
            tid, wv, l15, l4, srow, sch, xsw, xm, colh, gn);
  }
}

// ---------------- heads: exact fp32 VALU GEMM [1024 x 324 x 512] + epilogue --
__global__ __launch_bounds__(256) void heads_kernel(
    const float* __restrict__ hf,
    const float* __restrict__ lin_w, const float* __restrict__ lin_b,
    const float* __restrict__ lv_w,  const float* __restrict__ lv_b,
    const float* __restrict__ u_w,   const float* __restrict__ u_b,
    const float* __restrict__ ww_w,  const float* __restrict__ ww_b,
    const float* __restrict__ bf_w,  const float* __restrict__ bf_b,
    float* __restrict__ out)
{
  __shared__ float hs[64 * 513];
  const int tid = threadIdx.x;
  const int gb = blockIdx.x;     // 0..15
  const int cg = blockIdx.y;     // 0..5, 54 cols each
  for (int i = tid; i < 8192; i += 256) {
    fx4 v = *(const fx4*)(hf + (size_t)gb * 32768 + (size_t)i * 4);
    const int row = i >> 7;
    const int k = (i * 4) & 511;
    float* d = hs + row * 513 + k;
    d[0] = v[0]; d[1] = v[1]; d[2] = v[2]; d[3] = v[3];
  }
  __syncthreads();
  const int r = tid & 63;
  const int cq = tid >> 6;
  const float* hrow = hs + r * 513;
  const int b_ = gb * 64 + r;
#pragma unroll 1
  for (int j = 0; j < 14; ++j) {
    const int cl = cq + 4 * j;
    if (cl >= 54) break;
    const int C = cg * 54 + cl;      // 0..323
    const float* wp; float bv;
    if (C < 32)       { wp = lin_w + (size_t)C * 512;        bv = lin_b[C]; }
    else if (C < 64)  { wp = lv_w + (size_t)(C - 32) * 512;  bv = lv_b[C - 32]; }
    else if (C < 192) { wp = u_w + (size_t)(C - 64) * 512;   bv = u_b[C - 64]; }
    else if (C < 320) { wp = ww_w + (size_t)(C - 192) * 512; bv = ww_b[C - 192]; }
    else              { wp = bf_w + (size_t)(C - 320) * 512; bv = bf_b[C - 320]; }
    float dot = 0.f;
#pragma unroll 8
    for (int k = 0; k < 512; k += 4) {
      fx4 w = *(const fx4*)(wp + k);
      dot += hrow[k] * w[0] + hrow[k + 1] * w[1] + hrow[k + 2] * w[2] + hrow[k + 3] * w[3];
    }
    const float res = bv + dot;
    if (C < 32)       out[(size_t)b_ * 32 + C] = __builtin_amdgcn_exp2f(res * 1.44269504f) * 0.1f;
    else if (C < 64)  out[32768 + (size_t)b_ * 32 + (C - 32)] = res - 5.f;
    else if (C < 192) out[65536 + (size_t)b_ * 128 + (C - 64)] = res;
    else if (C < 320) out[196608 + (size_t)b_ * 128 + (C - 192)] = res;
    else              out[327680 + (size_t)b_ * 4 + (C - 320)] = res;
  }
}

extern "C" void kernel_launch(void* const* d_in, const int* in_sizes, int n_in,
                              void* d_out, int out_size, void* d_ws, size_t ws_size,
                              hipStream_t stream) {
  (void)in_sizes; (void)n_in; (void)out_size; (void)ws_size;
  const float* x     = (const float*)d_in[0];
  const float* a     = (const float*)d_in[1];
  const float* mask  = (const float*)d_in[2];
  const float* w_ih  = (const float*)d_in[3];
  const float* w_hh  = (const float*)d_in[4];
  const float* b_ih  = (const float*)d_in[5];
  const float* b_hh  = (const float*)d_in[6];
  const float* lin_w = (const float*)d_in[7];
  const float* lin_b = (const float*)d_in[8];
  const float* lv_w  = (const float*)d_in[9];
  const float* lv_b  = (const float*)d_in[10];
  const float* u_w   = (const float*)d_in[11];
  const float* u_b   = (const float*)d_in[12];
  const float* ww_w  = (const float*)d_in[13];
  const float* ww_b  = (const float*)d_in[14];
  const float* bf_w  = (const float*)d_in[15];
  const float* bf_b  = (const float*)d_in[16];

  char* ws = (char*)d_ws;
  short* yw       = (short*)(ws);                 // 33,554,432 B: [256][1024][64] bf16
  short* hbuf     = (short*)(ws + 33554432);      //  2,097,152 B: [2][1024][512] bf16
  float* hfinal   = (float*)(ws + 35651584);      //  2,097,152 B
  unsigned* ctr   = (unsigned*)(ws + 37748736);   //     36,864 B (flags region)

  hipMemsetAsync(hbuf, 0, 2097152, stream);       // both slots -> finite residue
  hipMemsetAsync(ctr, 0, 36864, stream);

  pack_y_kernel<<<1024, 256, 0, stream>>>(x, a, mask, yw);
  lstm_rec<<<256, 256, 0, stream>>>(yw, w_hh, w_ih, b_ih, b_hh, hbuf, hfinal, ctr);
  heads_kernel<<<dim3(16, 6), 256, 0, stream>>>(hfinal, lin_w, lin_b, lv_w, lv_b,
                                                u_w, u_b, ww_w, ww_b, bf_w, bf_b,
                                                (float*)d_out);
}